// Round 2
// 1063.095 us; speedup vs baseline: 5.2522x; 5.2522x over previous
//
#include <hip/hip_runtime.h>

// Hyena QA forward: 12 depthwise long-conv residual layers + LN + 2-logit head.
// Conv runs on the matrix cores: per channel,
//   y[256T + 16i + j] = sum_kk xpad2[256T + 16i + kk] * wext'[kk - j]
// with xpad2[u] = x[u-2048] (fp16, LDS) as MFMA A and the banded weight matrix
// wext'[m] = w[m-1] as MFMA B (v_mfma_f32_16x16x32_f16, fp32 accum).
// B's per-lane -j shift is served from 8 pre-shifted w-window rows in LDS
// (row r holds w shifted by -r; -8*(j>>3) stays 16B-aligned), rebuilt per
// 8-step block (double-buffered) from global w under the MFMAs.
// A-side reuse: A_T(s) = A_{T-1}(s+8) -> 32-slot register ring, 1 new
// ds_read_b128 per step feeds 4 MFMAs (4 tiles/wave, 4 waves = 16 tiles).
// Residual is re-read from global fp32, so only the conv product is fp16.

#define LSEQ   4095
#define DMODEL 768
#define KF     4095
#define CROW   4096
#define NCH    1536
#define BL     8190

typedef _Float16 f16x8 __attribute__((ext_vector_type(8)));
typedef _Float16 f16x4 __attribute__((ext_vector_type(4)));
typedef float    f32x4 __attribute__((ext_vector_type(4)));

// ---------------- embed: x[c=(b,d)][t] = emb[ids[b,t],d] + pos[t,d] ----------
__global__ __launch_bounds__(256)
void embed_kernel(const int* __restrict__ ids, const float* __restrict__ emb,
                  const float* __restrict__ pos, float* __restrict__ xout)
{
    __shared__ float tile[32 * 65];
    const int d0 = blockIdx.x * 64;
    const int t0 = blockIdx.y * 32;
    const int b  = blockIdx.z;
    const int tid = threadIdx.x;

    {   // read phase: coalesced along d
        const int lane = tid & 63, row = tid >> 6;
        #pragma unroll
        for (int r = 0; r < 8; ++r) {
            int tr = row * 8 + r;
            int t  = t0 + tr;
            if (t < LSEQ) {
                int id = ids[b * LSEQ + t];
                tile[tr * 65 + lane] =
                    emb[(size_t)id * DMODEL + d0 + lane] +
                    pos[(size_t)t  * DMODEL + d0 + lane];
            }
        }
    }
    __syncthreads();
    {   // write phase: coalesced along t
        const int lt = tid & 31, drow = tid >> 5;
        #pragma unroll
        for (int r = 0; r < 8; ++r) {
            int dr = drow * 8 + r;
            int t  = t0 + lt;
            if (t < LSEQ)
                xout[(size_t)(b * DMODEL + d0 + dr) * CROW + t] = tile[lt * 65 + dr];
        }
    }
}

// ---------------- one residual long-conv layer (MFMA) -------------------------
__global__ __launch_bounds__(256, 2)
void conv_kernel(const float* __restrict__ xin, float* __restrict__ xout,
                 const float* __restrict__ w, const float* __restrict__ bias)
{
    // xpad2: 1088 16B-chunks = 8704 fp16; zeros outside [2048, 6144)
    __shared__ __align__(16) _Float16 lxh[8704];
    // 2 x (8 rows x 264 elems) shifted-w windows (row r = w shifted by -r-1)
    __shared__ __align__(16) _Float16 wsh[2 * 2112];

    const int c    = blockIdx.x;                 // channel 0..1535 (b*768+d)
    const int du   = __builtin_amdgcn_readfirstlane(c % DMODEL);
    const int tid  = threadIdx.x;
    const size_t choff = (size_t)c * CROW;
    const float* __restrict__ wrow = w + (size_t)du * KF;
    const float* __restrict__ xrow = xin + choff;
    const float bv = bias[du];

    const int lane = tid & 63;
    const int wid  = tid >> 6;                   // 4 waves
    const int jj   = lane & 15;                  // A-row i / B-col j
    const int hh   = lane >> 4;                  // k-half group 0..3
    const int T0   = wid << 2;                   // 4 tiles per wave

    // A fragment elem offset: + 32*u per ring index u
    const int abase = 256 * T0 + 16 * jj + 8 * hh;
    // B fragment elem offset: row (j&7), -8*(j>>3) folded in; + 32*d per step
    const int bbase = 264 * (jj & 7) + 8 * (hh - (jj >> 3) + 1);

    // build shifted-w block bb into buffer bufi:
    // wsh[bufi][r][m] = w[256*bb - 9 + m - r],  m in [0,264)
    auto wbuild = [&](int bufi, int bb) {
        for (int cc = tid; cc < 264; cc += 256) {
            int r  = cc / 33;
            int q  = cc - 33 * r;
            int wb = 256 * bb - 9 + 8 * q - r;
            f16x8 hw;
            if (bb >= 1 && bb <= 14) {           // interior: fully in-bounds
                float4 va = *(const float4*)(wrow + wb);
                float4 vb = *(const float4*)(wrow + wb + 4);
                hw[0] = (_Float16)va.x; hw[1] = (_Float16)va.y;
                hw[2] = (_Float16)va.z; hw[3] = (_Float16)va.w;
                hw[4] = (_Float16)vb.x; hw[5] = (_Float16)vb.y;
                hw[6] = (_Float16)vb.z; hw[7] = (_Float16)vb.w;
            } else {                             // edges: guarded scalar
                #pragma unroll
                for (int e = 0; e < 8; ++e) {
                    int wi = wb + e;
                    hw[e] = (_Float16)(((unsigned)wi < 4095u) ? wrow[wi] : 0.0f);
                }
            }
            *(f16x8*)(wsh + bufi * 2112 + 264 * r + 8 * q) = hw;
        }
    };

    // ---- stage x -> lxh as fp16 (xpad2[u] = x[u-2048]); zero-fill pads ----
    {
        f16x8 z = {};
        *(f16x8*)(lxh + 8 * tid) = z;                    // chunks 0..255
        *(f16x8*)(lxh + 8 * (768 + tid)) = z;            // chunks 768..1023
        if (tid < 64) *(f16x8*)(lxh + 8 * (1024 + tid)) = z; // 1024..1087
        #pragma unroll
        for (int rr = 0; rr < 4; ++rr) {                 // x[0..4096), coalesced
            float4 a = ((const float4*)xrow)[tid + 256 * rr];
            f16x4 hv;
            hv[0] = (_Float16)a.x; hv[1] = (_Float16)a.y;
            hv[2] = (_Float16)a.z; hv[3] = (_Float16)a.w;
            *(f16x4*)(lxh + 2048 + 4 * (tid + 256 * rr)) = hv;
        }
    }
    wbuild(0, 0);
    __syncthreads();

    f32x4 acc[4];
    {
        f32x4 z4 = {};
        #pragma unroll
        for (int m = 0; m < 4; ++m) acc[m] = z4;
    }

    // A-ring prefill: slots u = 0..31
    f16x8 ring[32];
    #pragma unroll
    for (int u = 0; u < 32; ++u)
        ring[u] = *(const f16x8*)(lxh + abase + 32 * u);

    // one 8-step block: consume wsh[PH&1], build block BETA+1 into wsh[PH^1];
    // step s = 8*BETA + d; tile m uses ring slot (s + 8m)&31; after the 4
    // MFMAs, slot s&31 is refilled with frag u = s+32 (prefetch dist 8 steps).
#define BLOCK8(PH, BETA)                                                      \
    {                                                                         \
      wbuild(((PH) ^ 1) & 1, (BETA) + 1);                                     \
      _Pragma("unroll")                                                       \
      for (int d = 0; d < 8; ++d) {                                           \
        f16x8 bf = *(const f16x8*)(wsh + ((PH) & 1) * 2112 + bbase + 32 * d); \
        acc[0] = __builtin_amdgcn_mfma_f32_16x16x32_f16(                      \
                     ring[(8 * (PH) + d) & 31], bf, acc[0], 0, 0, 0);         \
        acc[1] = __builtin_amdgcn_mfma_f32_16x16x32_f16(                      \
                     ring[(8 * (PH) + d + 8) & 31], bf, acc[1], 0, 0, 0);     \
        acc[2] = __builtin_amdgcn_mfma_f32_16x16x32_f16(                      \
                     ring[(8 * (PH) + d + 16) & 31], bf, acc[2], 0, 0, 0);    \
        acc[3] = __builtin_amdgcn_mfma_f32_16x16x32_f16(                      \
                     ring[(8 * (PH) + d + 24) & 31], bf, acc[3], 0, 0, 0);    \
        ring[(8 * (PH) + d) & 31] =                                           \
            *(const f16x8*)(lxh + abase + 32 * (8 * (BETA) + d + 32));        \
      }                                                                       \
      __syncthreads();                                                        \
    }

    // 17 blocks = 136 K-steps (129 needed; tail B-frags are built as zeros)
    int beta = 0;
    #pragma unroll 1
    for (int s4 = 0; s4 < 4; ++s4) {
        BLOCK8(0, beta) ++beta;
        BLOCK8(1, beta) ++beta;
        BLOCK8(2, beta) ++beta;
        BLOCK8(3, beta) ++beta;
    }
    BLOCK8(0, 16)
#undef BLOCK8

    // ---- epilogue: residual (fp32 from global) + bias ----
    // C/D: col = lane&15 (j), row = 4*(lane>>4) + p  ->  t = 256T + 64h + 16p + j
    #pragma unroll
    for (int m = 0; m < 4; ++m) {
        int T = T0 + m;
        #pragma unroll
        for (int p = 0; p < 4; ++p) {
            int t = 256 * T + 64 * hh + 16 * p + jj;
            float v = acc[m][p] + bv + xrow[t];
            xout[choff + t] = (t < LSEQ) ? v : 0.0f;   // keep elem 4095 == 0
        }
    }
}

// ---------------- fused LayerNorm + (D x 2) head ------------------------------
__global__ __launch_bounds__(256)
void head_kernel(const float* __restrict__ x, const float* __restrict__ g,
                 const float* __restrict__ bb, const float* __restrict__ qw,
                 const float* __restrict__ qb, float* __restrict__ out)
{
    const int b = blockIdx.y;
    const int t = blockIdx.x * 256 + threadIdx.x;
    const bool valid = t < LSEQ;
    const int tt = valid ? t : 0;

    float s1 = 0.f, s2 = 0.f, q0 = 0.f, q1 = 0.f;
    float G0 = 0.f, G1 = 0.f, C0 = 0.f, C1 = 0.f;
    const float* xb = x + (size_t)b * DMODEL * CROW + tt;
    for (int dd = 0; dd < DMODEL; ++dd) {
        float xv = xb[(size_t)dd * CROW];
        float gd = g[dd], bd = bb[dd];
        float w0 = qw[2 * dd], w1 = qw[2 * dd + 1];
        s1 += xv;
        s2 = fmaf(xv, xv, s2);
        q0 = fmaf(xv, gd * w0, q0);
        q1 = fmaf(xv, gd * w1, q1);
        G0 = fmaf(gd, w0, G0); G1 = fmaf(gd, w1, G1);
        C0 = fmaf(bd, w0, C0); C1 = fmaf(bd, w1, C1);
    }
    float m   = s1 * (1.0f / 768.0f);
    float var = s2 * (1.0f / 768.0f) - m * m;
    float r   = rsqrtf(var + 1e-5f);
    float l0  = r * (q0 - m * G0) + C0 + qb[0];
    float l1  = r * (q1 - m * G1) + C1 + qb[1];
    if (valid) {
        out[(size_t)b * LSEQ + t] = l0;
        out[BL + (size_t)b * LSEQ + t] = l1;
    }
}

extern "C" void kernel_launch(void* const* d_in, const int* in_sizes, int n_in,
                              void* d_out, int out_size, void* d_ws, size_t ws_size,
                              hipStream_t stream)
{
    const int*   ids = (const int*)  d_in[0];
    const float* emb = (const float*)d_in[1];
    const float* pos = (const float*)d_in[2];
    const float* fw  = (const float*)d_in[3];
    const float* fb  = (const float*)d_in[4];
    const float* lg  = (const float*)d_in[5];
    const float* lb  = (const float*)d_in[6];
    const float* qw  = (const float*)d_in[7];
    const float* qb  = (const float*)d_in[8];
    float* out = (float*)d_out;

    const size_t bufElems = (size_t)NCH * CROW;
    if (ws_size < 2 * bufElems * sizeof(float)) return;

    float* bufA = (float*)d_ws;
    float* bufB = bufA + bufElems;
    // bufA row element 4095 must be 0 (embed writes only t<4095);
    // conv epilogue writes zeros there for all later buffers.
    hipMemsetAsync(bufA, 0, bufElems * sizeof(float), stream);

    embed_kernel<<<dim3(12, 128, 2), 256, 0, stream>>>(ids, emb, pos, bufA);

    const float* cur = bufA;
    float*       nxt = bufB;
    for (int l = 0; l < 12; ++l) {
        conv_kernel<<<NCH, 256, 0, stream>>>(cur, nxt,
                                             fw + (size_t)l * DMODEL * KF,
                                             fb + (size_t)l * DMODEL);
        const float* tmp = nxt;
        nxt = (float*)cur;
        cur = tmp;
    }
    head_kernel<<<dim3(16, 2), 256, 0, stream>>>(cur, lg, lb, qw, qb, out);
}